// Round 2
// baseline (217.269 us; speedup 1.0000x reference)
//
#include <hip/hip_runtime.h>
#include <math.h>

#define REC_LEN 49                 // 7x7 floats per (b,z)
#define NPOS 64                    // 4 pixels x 16 patches

// Compute the 64 patch values (k = (p1*2+p2)*16 + h*4 + w) from a 7x7 record.
// Bilinear 7->8 resize (jax.image.resize): edge outputs collapse to edge input;
// interior weights are exact sixteenths.
__device__ __forceinline__ void patchvals(const float* __restrict__ in, float* __restrict__ out) {
    const float wA[8] = {1.f, 0.1875f, 0.3125f, 0.4375f, 0.5625f, 0.6875f, 0.8125f, 1.f};
    const float wB[8] = {0.f, 0.8125f, 0.6875f, 0.5625f, 0.4375f, 0.3125f, 0.1875f, 0.f};
    const int  i0[8]  = {0, 0, 1, 2, 3, 4, 5, 6};
    const int  i1[8]  = {0, 1, 2, 3, 4, 5, 6, 6};
#pragma unroll
    for (int r = 0; r < 8; ++r) {
        float tmp[7];
#pragma unroll
        for (int c = 0; c < 7; ++c)
            tmp[c] = wA[r] * in[i0[r] * 7 + c] + wB[r] * in[i1[r] * 7 + c];
#pragma unroll
        for (int c = 0; c < 8; ++c) {
            float vv = wA[c] * tmp[i0[c]] + wB[c] * tmp[i1[c]];
            int k = (((r & 1) * 2 + (c & 1)) << 4) + ((r >> 1) << 2) + (c >> 1);
            out[k] = vv;   // constant index after full unroll -> stays in VGPRs
        }
    }
}

// Record r = 4*lane + W. Float start = 196*lane + 49*W; aligned window start =
// 196*lane + 48*W (16B-aligned for every lane; W is wave-uniform and a
// compile-time constant here, so all indexing stays in registers).
template<int W>
__device__ __forceinline__ void load_rec(const float* __restrict__ xblk, int lane, float* __restrict__ in) {
    const float4* p = (const float4*)xblk + 49 * lane + 12 * W;
    float4 f[13];
#pragma unroll
    for (int i = 0; i < 13; ++i) f[i] = p[i];
    const float* ff = (const float*)f;
#pragma unroll
    for (int j = 0; j < 49; ++j) in[j] = ff[W + j];   // W+j compile-time
}

#define LOAD_REC_SWITCH(xblk, lane, in, w)            \
    switch (w) {                                      \
        case 0:  load_rec<0>(xblk, lane, in); break;  \
        case 1:  load_rec<1>(xblk, lane, in); break;  \
        case 2:  load_rec<2>(xblk, lane, in); break;  \
        default: load_rec<3>(xblk, lane, in); break;  \
    }

// Butterfly component-fold across the 64 lanes of a wave:
// in : a[c] = this lane's value of component c (c = 0..63)
// out: a[0] on lane l = sum over all 64 lanes of component l.
// All array indices compile-time (cndmask selects, not indexed loads).
__device__ __forceinline__ void fold64(float* a, int lane) {
#pragma unroll
    for (int m = 32; m >= 1; m >>= 1) {
        const bool hi = (lane & m) != 0;
#pragma unroll
        for (int i = 0; i < m; ++i) {
            float x0 = a[i], x1 = a[i + m];
            float mine  = hi ? x1 : x0;
            float other = hi ? x0 : x1;
            a[i] = mine + __shfl_xor(other, m, 64);
        }
    }
}

// ---------------- Kernel A: per-block {sum, sumsq} over 256 z's ----------------
extern "C" __global__ void __launch_bounds__(256)
k_stats(const float* __restrict__ x, float* __restrict__ part) {
    const int tid = threadIdx.x;
    const int lane = tid & 63, w = tid >> 6;
    const float* xblk = x + (size_t)blockIdx.x * (256 * REC_LEN);

    float in[REC_LEN];
    LOAD_REC_SWITCH(xblk, lane, in, w);

    float v[NPOS];
    patchvals(in, v);
    float sq[NPOS];
#pragma unroll
    for (int k = 0; k < NPOS; ++k) sq[k] = v[k] * v[k];

    fold64(v, lane);    // lane l: wave-sum of component l
    fold64(sq, lane);

    __shared__ float red[4][2][64];   // 2 KB
    red[w][0][lane] = v[0];
    red[w][1][lane] = sq[0];
    __syncthreads();
    if (tid < 64) {
        float s  = red[0][0][tid] + red[1][0][tid] + red[2][0][tid] + red[3][0][tid];
        float s2 = red[0][1][tid] + red[1][1][tid] + red[2][1][tid] + red[3][1][tid];
        part[(size_t)blockIdx.x * 128 + tid]      = s;
        part[(size_t)blockIdx.x * 128 + 64 + tid] = s2;
    }
}

// ---------------- Kernel B: finalize per (b,z) ----------------
extern "C" __global__ void __launch_bounds__(256)
k_final(const float* __restrict__ x, const float* __restrict__ Wl,
        const float* __restrict__ part, float* __restrict__ out) {
    __shared__ float msh[NPOS], ish[NPOS];
    const int tid = threadIdx.x;
    const int lane = tid & 63, w = tid >> 6;
    const int b = blockIdx.x >> 3;   // 8 z-chunks per b
    const float* xblk = x + (size_t)blockIdx.x * (256 * REC_LEN);

    // Issue global loads first so they overlap the partials fold below.
    float in[REC_LEN];
    LOAD_REC_SWITCH(xblk, lane, in, w);

    if (tid < 64) {
        float s = 0.f, s2 = 0.f;
#pragma unroll
        for (int c = 0; c < 8; ++c) {
            const float* p = part + (size_t)(b * 8 + c) * 128;
            s  += p[tid];
            s2 += p[64 + tid];
        }
        float m   = s * (1.f / 2048.f);
        float var = fmaf(-m, m, s2 * (1.f / 2048.f));
        msh[tid] = m;
        ish[tid] = var > 0.f ? rsqrtf(var) : 0.f;  // nan_to_num: degenerate -> 0
    }
    __syncthreads();

    float v[NPOS];
    patchvals(in, v);

    // zscore over channels (k uniform across lanes -> LDS broadcast, free)
#pragma unroll
    for (int k = 0; k < NPOS; ++k)
        v[k] = (v[k] - msh[k]) * ish[k];

    const float w0 = Wl[0], w1 = Wl[1], w2 = Wl[2], w3 = Wl[3], w4 = Wl[4];
    float zz = 0.f, sp0 = 0.f, sp1 = 0.f, sp2 = 0.f, sp3 = 0.f;
#pragma unroll
    for (int n = 0; n < 16; ++n) {
        float a0 = v[n], a1 = v[16 + n], a2 = v[32 + n], a3 = v[48 + n];
        // zscore over the 4 pixels (deviations then sumsq: stable)
        float m4 = 0.25f * (a0 + a1 + a2 + a3);
        float d0 = a0 - m4, d1 = a1 - m4, d2 = a2 - m4, d3 = a3 - m4;
        float var4 = 0.25f * (d0 * d0 + d1 * d1 + d2 * d2 + d3 * d3);
        float inv4 = var4 > 0.f ? rsqrtf(var4) : 0.f;   // nan_to_num
        float x0 = d0 * inv4, x1 = d1 * inv4, x2 = d2 * inv4, x3 = d3 * inv4;
        // ELM hidden (bias row first in Xb)
        float t = w0 + w1 * x0 + w2 * x1 + w3 * x2 + w4 * x3;
        float h = 1.f / (1.f + expf(-t));
        zz += h * h;
        sp0 += x0 * h; sp1 += x1 * h; sp2 += x2 * h; sp3 += x3 * h;
    }
    float izz = 1.f / zz;   // h>0 -> zz>0
    float b0 = sp0 * izz, b1 = sp1 * izz, b2 = sp2 * izz, b3 = sp3 * izz;
    float mb = 0.25f * (b0 + b1 + b2 + b3);
    float e0 = b0 - mb, e1 = b1 - mb, e2 = b2 - mb, e3 = b3 - mb;
    out[(size_t)blockIdx.x * 256 + 4 * lane + w] =
        sqrtf(0.25f * (e0 * e0 + e1 * e1 + e2 * e2 + e3 * e3));
}

extern "C" void kernel_launch(void* const* d_in, const int* in_sizes, int n_in,
                              void* d_out, int out_size, void* d_ws, size_t ws_size,
                              hipStream_t stream) {
    (void)in_sizes; (void)n_in; (void)out_size; (void)ws_size;
    const float* x  = (const float*)d_in[0];
    const float* Wl = (const float*)d_in[1];
    float* out  = (float*)d_out;
    float* part = (float*)d_ws;          // 2048 * 128 floats = 1 MB scratch

    k_stats<<<2048, 256, 0, stream>>>(x, part);
    k_final<<<2048, 256, 0, stream>>>(x, Wl, part, out);
}